// Round 1
// baseline (832.594 us; speedup 1.0000x reference)
//
#include <hip/hip_runtime.h>

// select_decoder_vectors: out[i,:] = values[i] * W_D[layer_idx[i], feat_idx[i], :]
// Shapes: W_D (12, 16384, 768) f32, nnz = 131072, d_model = 768.
// Memory-bound gather: one wave (64 lanes) per nnz row; 768 floats = 192 float4,
// lane handles float4 #{lane, lane+64, lane+128} -> 16B/lane coalesced ld/st.

#define D_MODEL 768
#define D_SAE   16384
#define NVEC    (D_MODEL / 4)   // 192 float4 per row
#define WAVES_PER_BLOCK 4

__global__ __launch_bounds__(256) void gather_scale_kernel(
    const float* __restrict__ W_D,
    const float* __restrict__ values,
    const int*   __restrict__ layer_idx,
    const int*   __restrict__ feat_idx,
    float*       __restrict__ out,
    int nnz)
{
    const int wave_in_block = threadIdx.x >> 6;
    const int lane          = threadIdx.x & 63;
    const int row           = blockIdx.x * WAVES_PER_BLOCK + wave_in_block;
    if (row >= nnz) return;

    const float v = values[row];
    const long long src_row = ((long long)layer_idx[row] * D_SAE + feat_idx[row]);

    const float4* __restrict__ src = (const float4*)(W_D + src_row * D_MODEL);
    float4* __restrict__ dst       = (float4*)(out + (long long)row * D_MODEL);

    #pragma unroll
    for (int i = 0; i < 3; ++i) {
        float4 x = src[lane + 64 * i];
        x.x *= v; x.y *= v; x.z *= v; x.w *= v;
        dst[lane + 64 * i] = x;
    }
}

extern "C" void kernel_launch(void* const* d_in, const int* in_sizes, int n_in,
                              void* d_out, int out_size, void* d_ws, size_t ws_size,
                              hipStream_t stream) {
    const float* W_D       = (const float*)d_in[0];
    const float* values    = (const float*)d_in[1];
    const int*   layer_idx = (const int*)d_in[2];
    // d_in[3] = pos_idx (unused by reference)
    const int*   feat_idx  = (const int*)d_in[4];
    float*       out       = (float*)d_out;

    const int nnz = in_sizes[1];  // 131072
    const int blocks = (nnz + WAVES_PER_BLOCK - 1) / WAVES_PER_BLOCK;
    gather_scale_kernel<<<blocks, 256, 0, stream>>>(W_D, values, layer_idx, feat_idx, out, nnz);
}